// Round 5
// baseline (181.148 us; speedup 1.0000x reference)
//
#include <hip/hip_runtime.h>
#include <hip/hip_bf16.h>
#include <cstddef>
#include <cstdint>

#define B_ 2
#define S_ 2048
#define E_ 1024
#define H_ 16
#define D_ 64
#define WIN_ 3

using bf16x8 = __attribute__((ext_vector_type(8))) short;  // 8 bf16 = 4 VGPRs
using f32x4  = __attribute__((ext_vector_type(4))) float;  // MFMA C/D
using uintx2 = __attribute__((ext_vector_type(2))) unsigned int;

static __device__ __forceinline__ unsigned short f2bf(float f) {
    union { float f; unsigned int u; } c; c.f = f;
    unsigned int r = c.u + 0x7FFF + ((c.u >> 16) & 1);   // round-to-nearest-even
    return (unsigned short)(r >> 16);
}

static __device__ __forceinline__ void gload16(const void* g, void* l) {
    __builtin_amdgcn_global_load_lds(
        (const __attribute__((address_space(1))) void*)g,
        (__attribute__((address_space(3))) void*)l, 16, 0, 0);
}

static __device__ __forceinline__ unsigned int cvt_pk_bf16(float a, float b) {
    unsigned int d;
    asm("v_cvt_pk_bf16_f32 %0, %1, %2" : "=v"(d) : "v"(a), "v"(b));
    return d;  // lo half = bf16(a), hi half = bf16(b)
}

// XOR-swizzled LDS index (shorts) for [row][chunk-of-8-shorts] tiles with
// 64-short rows: slot = chunk ^ (row & 7). Breaks the 128B-row bank aliasing
// while staying global_load_lds-compatible (lane*16B contiguous).
#define SWZ(row, c) ((((row) * 8) + ((c) ^ ((row) & 7))) * 8)

// ---------------------------------------------------------------------------
// fp32 -> bf16 cast: y=0: x (4M elems), y=1..3: Wq/Wk/Wv (1M each)
// ---------------------------------------------------------------------------
__global__ __launch_bounds__(256) void cast_kernel(
    const float* __restrict__ X,  const float* __restrict__ Wq,
    const float* __restrict__ Wk, const float* __restrict__ Wv,
    unsigned short* __restrict__ xb,  unsigned short* __restrict__ wqb,
    unsigned short* __restrict__ wkb, unsigned short* __restrict__ wvb)
{
    const float* src; unsigned short* dst; int n;
    switch (blockIdx.y) {
        case 0:  src = X;  dst = xb;  n = B_ * S_ * E_; break;
        case 1:  src = Wq; dst = wqb; n = E_ * E_;      break;
        case 2:  src = Wk; dst = wkb; n = E_ * E_;      break;
        default: src = Wv; dst = wvb; n = E_ * E_;      break;
    }
    int i = (blockIdx.x * 256 + threadIdx.x) * 8;
    if (i >= n) return;
    float4 a = *(const float4*)(src + i);
    float4 b = *(const float4*)(src + i + 4);
    ushort4 lo, hi;
    lo.x = f2bf(a.x); lo.y = f2bf(a.y); lo.z = f2bf(a.z); lo.w = f2bf(a.w);
    hi.x = f2bf(b.x); hi.y = f2bf(b.y); hi.z = f2bf(b.z); hi.w = f2bf(b.w);
    *(ushort4*)(dst + i)     = lo;
    *(ushort4*)(dst + i + 4) = hi;
}

// ---------------------------------------------------------------------------
// bf16 MFMA projection GEMM (m97 structure + swizzled LDS):
// C[i,j] = sum_k A[i,k]*B[j,k]; 128x128 tile, BK=64, 4 waves, 4x4 frags.
// z=0: A=x, B=Wq -> q bf16 [B,H,S,D] scaled log2(e)/8 (exp2 softmax path)
// z=1: A=x, B=Wk -> k bf16 [B,H,S,D]
// z=2: A=Wv, B=x (swapped) -> v bf16 [B,H,D,S] with coalesced stores
// ---------------------------------------------------------------------------
__global__ __launch_bounds__(256, 4) void gemm_kernel(
    const unsigned short* __restrict__ xb,
    const unsigned short* __restrict__ wqb, const unsigned short* __restrict__ wkb,
    const unsigned short* __restrict__ wvb,
    const float* __restrict__ bq, const float* __restrict__ bk,
    const float* __restrict__ bv,
    unsigned short* __restrict__ qb, unsigned short* __restrict__ kb,
    unsigned short* __restrict__ vb)
{
    constexpr int BM = 128, BK = 64;
    __shared__ unsigned short As[BM * BK];
    __shared__ unsigned short Bs[BM * BK];

    const int t    = threadIdx.x;
    const int lane = t & 63;
    const int w    = t >> 6;
    const int l15  = lane & 15;
    const int quad = lane >> 4;
    const int wm   = w & 1;
    const int wn   = w >> 1;
    const int m0   = blockIdx.x * BM;
    const int n0   = blockIdx.y * BM;
    const int z    = blockIdx.z;

    const unsigned short *Ab, *Bb; const float* bias; unsigned short* outp;
    int i0, j0; float sc = 1.0f;
    if (z == 0)      { Ab = xb;  Bb = wqb; bias = bq; outp = qb; i0 = m0; j0 = n0;
                       sc = 0.125f * 1.44269504088896f; }
    else if (z == 1) { Ab = xb;  Bb = wkb; bias = bk; outp = kb; i0 = m0; j0 = n0; }
    else             { Ab = wvb; Bb = xb;  bias = bv; outp = vb; i0 = n0; j0 = m0; }

    const int lrow = lane >> 3;
    const int gch  = ((lane & 7) ^ (lrow & 7)) * 8;
    const int lsl  = (lane & 7) * 8;

    f32x4 acc[4][4];
    #pragma unroll
    for (int mt = 0; mt < 4; ++mt)
        #pragma unroll
        for (int nt = 0; nt < 4; ++nt)
            #pragma unroll
            for (int r = 0; r < 4; ++r) acc[mt][nt][r] = 0.f;

    for (int k0 = 0; k0 < E_; k0 += BK) {
        __syncthreads();
        #pragma unroll
        for (int is = 0; is < 4; ++is) {
            int r = (w * 4 + is) * 8 + lrow;
            gload16(Ab + (size_t)(i0 + r) * E_ + k0 + gch, &As[r * BK + lsl]);
            gload16(Bb + (size_t)(j0 + r) * E_ + k0 + gch, &Bs[r * BK + lsl]);
        }
        __syncthreads();

        #pragma unroll
        for (int ks = 0; ks < 2; ++ks) {
            bf16x8 af[4], bfr[4];
            #pragma unroll
            for (int mt = 0; mt < 4; ++mt)
                af[mt] = *(const bf16x8*)&As[SWZ(wm*64 + mt*16 + l15, ks*4 + quad)];
            #pragma unroll
            for (int nt = 0; nt < 4; ++nt)
                bfr[nt] = *(const bf16x8*)&Bs[SWZ(wn*64 + nt*16 + l15, ks*4 + quad)];
            #pragma unroll
            for (int mt = 0; mt < 4; ++mt)
                #pragma unroll
                for (int nt = 0; nt < 4; ++nt)
                    acc[mt][nt] = __builtin_amdgcn_mfma_f32_16x16x32_bf16(
                        af[mt], bfr[nt], acc[mt][nt], 0, 0, 0);
        }
    }

    if (z < 2) {
        float bj[4];
        #pragma unroll
        for (int nt = 0; nt < 4; ++nt) bj[nt] = bias[j0 + wn*64 + nt*16 + l15];
        #pragma unroll
        for (int mt = 0; mt < 4; ++mt) {
            #pragma unroll
            for (int r = 0; r < 4; ++r) {
                int i = i0 + wm*64 + mt*16 + quad*4 + r;
                int b = i >> 11, s = i & (S_ - 1);
                #pragma unroll
                for (int nt = 0; nt < 4; ++nt) {
                    int jj = j0 + wn*64 + nt*16 + l15;
                    int hh = jj >> 6, d = jj & 63;
                    outp[(((size_t)(b * H_ + hh) * S_) + s) * D_ + d] =
                        f2bf((acc[mt][nt][r] + bj[nt]) * sc);
                }
            }
        }
    } else {
        #pragma unroll
        for (int mt = 0; mt < 4; ++mt) {
            #pragma unroll
            for (int r = 0; r < 4; ++r) {
                int i = i0 + wm*64 + mt*16 + quad*4 + r;
                int hh = i >> 6, d = i & 63;
                float bi = bias[i];
                #pragma unroll
                for (int nt = 0; nt < 4; ++nt) {
                    int jj = j0 + wn*64 + nt*16 + l15;
                    int b = jj >> 11, s = jj & (S_ - 1);
                    outp[(((size_t)(b * H_ + hh) * D_) + d) * S_ + s] =
                        f2bf(acc[mt][nt][r] + bi);
                }
            }
        }
    }
}

// ---------------------------------------------------------------------------
// MFMA attention, R13: R9 skeleton + V-direct-from-L2 (K stays LDS-staged).
//
// R12 post-mortem: mt=4 @ 1 block/CU (68.7us) lost to R9's mt=2 @ 2 blocks/CU
// (48.2us) -- LDS relief didn't pay for halved occupancy. R9 geometry is the
// local optimum; its LDS pipe (~27us of 48) splits evenly between K-frag and
// V-frag ds_reads. V has huge latency slack (consumed at iteration end) and
// its per-XCD working set is ~1MB (4 bh x 256KB, L2-resident via the XCD
// swizzle). So: V-frags move to direct global(L2) vector loads on the idle
// TA pipe; K keeps fast ds_reads for the latency-critical QK chain (this is
// what R10 got wrong -- it made K direct too and died on the QK dep chain).
//
// Per wave-iter: 8 ds_read_b128 (K only, was 16), 8 global bf16x8 V loads
// (ks=0 batch issued before exp/pack, ks=1 before PV -- ~300-400cy cover
// each, split keeps peak VGPR ~120 under the (512,4) 128-cap; spill guard:
// WRITE_SIZE). LDS = 32KB K dbuf + Dex -> 33KB, still 2 blocks/CU.
// Staging: 2 gload16/thread (was 4). Epilogue: Oex aliases the whole KV.
// Everything else byte-identical to R9 (proven 48.2us).
// q pre-scaled by log2(e)/8 in gemm -> raw v_exp_f32 here.
// XCD swizzle: bh = (j&7)*4 + (j>>7) keeps each XCD on 4 bh (L2-resident).
// ---------------------------------------------------------------------------
__global__ __launch_bounds__(512, 4) void attn_kernel(
    const unsigned short* __restrict__ Q, const unsigned short* __restrict__ K,
    const unsigned short* __restrict__ V, float* __restrict__ out)
{
    constexpr int TQ = 128, TK = 128;
    // per buffer (8192 shorts = 16KB): Ks0 @0 (keys 0..63), Ks1 @4096 (64..127)
    __shared__ unsigned short KV[2][8192];
    __shared__ float          Dex[TQ];

    const int t    = threadIdx.x;
    const int lane = t & 63;
    const int w    = t >> 6;        // wave 0..7
    const int wq   = w & 3;         // q-group (32 rows)
    const int wk   = w >> 2;        // key half
    const int l15  = lane & 15;
    const int quad = lane >> 4;

    const int j    = blockIdx.x;
    const int bh   = (j & 7) * 4 + (j >> 7);
    const int q0   = ((j >> 3) & 15) * TQ;
    const int wq0  = q0 + wq * 32;  // this wave's query base (32 rows)

    const unsigned short* Qp = Q + (size_t)bh * S_ * D_;
    const unsigned short* Kp = K + (size_t)bh * S_ * D_;
    const unsigned short* Vp = V + (size_t)bh * D_ * S_;   // [d][s]

    // Q B-operand frags (n = q = l15), pre-scaled by log2(e)/8: [mt][ks]
    bf16x8 qf[2][2];
    #pragma unroll
    for (int mt = 0; mt < 2; ++mt)
        #pragma unroll
        for (int ks = 0; ks < 2; ++ks)
            qf[mt][ks] = *(const bf16x8*)(Qp + (size_t)(wq0 + mt*16 + l15) * D_
                                          + ks*32 + quad*8);

    bf16x8 ones;
    #pragma unroll
    for (int i = 0; i < 8; ++i) ones[i] = (short)0x3F80;   // bf16 1.0

    f32x4 Oacc[2][4];
    #pragma unroll
    for (int mt = 0; mt < 2; ++mt)
        #pragma unroll
        for (int nt = 0; nt < 4; ++nt)
            #pragma unroll
            for (int r = 0; r < 4; ++r) Oacc[mt][nt][r] = 0.f;
    f32x4 Dacc[2];
    #pragma unroll
    for (int mt = 0; mt < 2; ++mt)
        #pragma unroll
        for (int r = 0; r < 4; ++r) Dacc[mt][r] = 0.f;

    // K staging: 512 threads, 1 gload16 per half; rows 0..63
    const int srow = t >> 3;                          // 0..63
    const int gch  = ((t & 7) ^ (srow & 7)) * 8;      // swizzle-inverse (shorts)
    const unsigned short* kg0 = Kp + (size_t)srow * D_ + gch;          // keys 0..63
    const unsigned short* kg1 = Kp + (size_t)(srow + 64) * D_ + gch;   // keys 64..127

    // V direct-read base for this wave: row d = nt*16+l15, keys wk*64+ks*32+quad*8
    const unsigned short* vbase = Vp + (size_t)l15 * S_ + wk*64 + quad*8;

    // prologue: stage K tile 0 into buffer 0
    {
        unsigned short* nb = KV[0];
        gload16(kg0, nb + t*8);
        gload16(kg1, nb + 4096 + t*8);
        kg0 += TK * D_; kg1 += TK * D_;
    }
    __syncthreads();                 // vmcnt drained -> buf0 ready

    int cur = 0;
    for (int k0 = 0; k0 < S_; k0 += TK) {
        // issue next-tile K staging into the other buffer (overlaps compute)
        if (k0 + TK < S_) {
            unsigned short* nb = KV[cur ^ 1];
            gload16(kg0, nb + t*8);
            gload16(kg1, nb + 4096 + t*8);
            kg0 += TK * D_; kg1 += TK * D_;
        }
        const unsigned short* KsW = &KV[cur][wk * 4096];

        // ---- S^T = K Q^T : 64 keys (4 kt of 16) x 32 q (2 mt) per wave ----
        f32x4 sacc[2][4];
        #pragma unroll
        for (int mt = 0; mt < 2; ++mt)
            #pragma unroll
            for (int kt = 0; kt < 4; ++kt)
                #pragma unroll
                for (int r = 0; r < 4; ++r) sacc[mt][kt][r] = 0.f;
        #pragma unroll
        for (int kt = 0; kt < 4; ++kt) {
            bf16x8 kf0 = *(const bf16x8*)&KsW[SWZ(kt*16 + l15, quad)];
            bf16x8 kf1 = *(const bf16x8*)&KsW[SWZ(kt*16 + l15, 4 + quad)];
            #pragma unroll
            for (int mt = 0; mt < 2; ++mt) {
                sacc[mt][kt] = __builtin_amdgcn_mfma_f32_16x16x32_bf16(
                    kf0, qf[mt][0], sacc[mt][kt], 0, 0, 0);
                sacc[mt][kt] = __builtin_amdgcn_mfma_f32_16x16x32_bf16(
                    kf1, qf[mt][1], sacc[mt][kt], 0, 0, 0);
            }
        }

        // ---- issue V (ks=0) loads early: ~exp/pack phase covers L2 latency -
        bf16x8 vf0[4];
        #pragma unroll
        for (int nt = 0; nt < 4; ++nt)
            vf0[nt] = *(const bf16x8*)(vbase + (size_t)(nt*16) * S_ + k0);

        // ---- exp2 + (rare) inverted-window mask; pack to bf16 in-register --
        unsigned int dw[2][4][2];
        #pragma unroll
        for (int mt = 0; mt < 2; ++mt) {
            const int qt0 = wq0 + mt*16;
            #pragma unroll
            for (int kt = 0; kt < 4; ++kt) {
                const int kt0 = k0 + wk*64 + kt*16;
                const bool band = (unsigned)(qt0 - kt0 + 18) <= 36u;  // wave-uniform
                float p[4];
                if (band) {
                    #pragma unroll
                    for (int r = 0; r < 4; ++r) {
                        int dlt = (qt0 + l15) - (kt0 + quad*4 + r);
                        if (dlt < 0) dlt = -dlt;
                        p[r] = (dlt <= WIN_) ? 0.f
                             : __builtin_amdgcn_exp2f(sacc[mt][kt][r]);
                    }
                } else {
                    #pragma unroll
                    for (int r = 0; r < 4; ++r)
                        p[r] = __builtin_amdgcn_exp2f(sacc[mt][kt][r]);
                }
                dw[mt][kt][0] = cvt_pk_bf16(p[0], p[1]);   // keys quad*4+{0,1}
                dw[mt][kt][1] = cvt_pk_bf16(p[2], p[3]);   // keys quad*4+{2,3}
            }
        }

        // ---- lane-swap P into PV A-frags: lane needs keys ks*32+quad*8..+7 -
        bf16x8 pa[2][2];
        #pragma unroll
        for (int mt = 0; mt < 2; ++mt) {
            #pragma unroll
            for (int ks = 0; ks < 2; ++ks) {
                uintx2 s0 = __builtin_amdgcn_permlane32_swap(
                    dw[mt][2*ks][0], dw[mt][2*ks + 1][0], false, false);
                uintx2 a02 = __builtin_amdgcn_permlane16_swap(
                    s0.x, s0.y, false, false);
                uintx2 s1 = __builtin_amdgcn_permlane32_swap(
                    dw[mt][2*ks][1], dw[mt][2*ks + 1][1], false, false);
                uintx2 a13 = __builtin_amdgcn_permlane16_swap(
                    s1.x, s1.y, false, false);
                union { unsigned int d[4]; bf16x8 v; } u;
                u.d[0] = a02.x;   // keys quad*8+{0,1}
                u.d[1] = a13.x;   // keys quad*8+{2,3}
                u.d[2] = a02.y;   // keys quad*8+{4,5}
                u.d[3] = a13.y;   // keys quad*8+{6,7}
                pa[mt][ks] = u.v;
            }
        }

        // ---- O += P V ; D += P 1 over this wave's key half ----
        // ks=0 uses vf0 (issued pre-exp); ks=1 loads issued here, consumed
        // after the ks=0 MFMA block (~150cy additional cover).
        bf16x8 vf1[4];
        #pragma unroll
        for (int nt = 0; nt < 4; ++nt)
            vf1[nt] = *(const bf16x8*)(vbase + (size_t)(nt*16) * S_ + k0 + 32);

        #pragma unroll
        for (int mt = 0; mt < 2; ++mt) {
            Dacc[mt] = __builtin_amdgcn_mfma_f32_16x16x32_bf16(
                pa[mt][0], ones, Dacc[mt], 0, 0, 0);
            Dacc[mt] = __builtin_amdgcn_mfma_f32_16x16x32_bf16(
                pa[mt][1], ones, Dacc[mt], 0, 0, 0);
        }
        #pragma unroll
        for (int nt = 0; nt < 4; ++nt)
            #pragma unroll
            for (int mt = 0; mt < 2; ++mt)
                Oacc[mt][nt] = __builtin_amdgcn_mfma_f32_16x16x32_bf16(
                    pa[mt][0], vf0[nt], Oacc[mt][nt], 0, 0, 0);
        #pragma unroll
        for (int nt = 0; nt < 4; ++nt)
            #pragma unroll
            for (int mt = 0; mt < 2; ++mt)
                Oacc[mt][nt] = __builtin_amdgcn_mfma_f32_16x16x32_bf16(
                    pa[mt][1], vf1[nt], Oacc[mt][nt], 0, 0, 0);

        __syncthreads();   // all waves done with KV[cur]; next buffer's loads
                           // drained by the barrier's vmcnt(0)
        cur ^= 1;
    }

    // ---- merge key halves through LDS (Oex spans both KV buffers; 32 KB) ----
    float* Oex = (float*)KV;             // 8192 floats = 32 KB
    if (wk == 1) {
        #pragma unroll
        for (int mt = 0; mt < 2; ++mt) {
            #pragma unroll
            for (int r = 0; r < 4; ++r) {
                const int qrow = wq*32 + mt*16 + quad*4 + r;
                Dex[qrow] = Dacc[mt][r];             // 16 lanes same value: benign
                #pragma unroll
                for (int nt = 0; nt < 4; ++nt)
                    Oex[qrow * 64 + nt*16 + l15] = Oacc[mt][nt][r];
            }
        }
    }
    __syncthreads();                     // Oex/Dex visible
    if (wk == 0) {
        const int b  = bh >> 4;
        const int hh = bh & 15;
        #pragma unroll
        for (int mt = 0; mt < 2; ++mt) {
            #pragma unroll
            for (int r = 0; r < 4; ++r) {
                const int qrow = wq*32 + mt*16 + quad*4 + r;
                const float iv = 1.f / (Dacc[mt][r] + Dex[qrow]);
                const int qg = q0 + qrow;
                float* op = out + (((size_t)b * S_ + qg) * H_ + hh) * D_;
                #pragma unroll
                for (int nt = 0; nt < 4; ++nt)
                    op[nt*16 + l15] =
                        (Oacc[mt][nt][r] + Oex[qrow * 64 + nt*16 + l15]) * iv;
            }
        }
    }
}

extern "C" void kernel_launch(void* const* d_in, const int* in_sizes, int n_in,
                              void* d_out, int out_size, void* d_ws, size_t ws_size,
                              hipStream_t stream) {
    const float* x  = (const float*)d_in[0];
    const float* Wq = (const float*)d_in[1];
    const float* bq = (const float*)d_in[2];
    const float* Wk = (const float*)d_in[3];
    const float* bk = (const float*)d_in[4];
    const float* Wv = (const float*)d_in[5];
    const float* bv = (const float*)d_in[6];
    float* out = (float*)d_out;

    const size_t per = (size_t)B_ * H_ * S_ * D_;   // 4,194,304 elements
    const size_t wsz = (size_t)E_ * E_;             // 1,048,576
    unsigned short* qb  = (unsigned short*)d_ws;
    unsigned short* kb  = qb + per;
    unsigned short* vb  = kb + per;
    unsigned short* xbf = vb + per;
    unsigned short* wqb = xbf + per;
    unsigned short* wkb = wqb + wsz;
    unsigned short* wvb = wkb + wsz;

    dim3 cgrid((B_ * S_ * E_ + 2047) / 2048, 4);
    cast_kernel<<<cgrid, 256, 0, stream>>>(x, Wq, Wk, Wv, xbf, wqb, wkb, wvb);

    dim3 ggrid(B_ * S_ / 128, E_ / 128, 3);
    gemm_kernel<<<ggrid, 256, 0, stream>>>(xbf, wqb, wkb, wvb, bq, bk, bv, qb, kb, vb);

    attn_kernel<<<dim3(512), 512, 0, stream>>>(qb, kb, vb, out);
}

// Round 6
// 155.141 us; speedup vs baseline: 1.1676x; 1.1676x over previous
//
#include <hip/hip_runtime.h>
#include <hip/hip_bf16.h>
#include <cstddef>
#include <cstdint>

#define B_ 2
#define S_ 2048
#define E_ 1024
#define H_ 16
#define D_ 64
#define WIN_ 3

using bf16x8 = __attribute__((ext_vector_type(8))) short;  // 8 bf16 = 4 VGPRs
using f32x4  = __attribute__((ext_vector_type(4))) float;  // MFMA C/D
using uintx2 = __attribute__((ext_vector_type(2))) unsigned int;

static __device__ __forceinline__ unsigned short f2bf(float f) {
    union { float f; unsigned int u; } c; c.f = f;
    unsigned int r = c.u + 0x7FFF + ((c.u >> 16) & 1);   // round-to-nearest-even
    return (unsigned short)(r >> 16);
}

static __device__ __forceinline__ void gload16(const void* g, void* l) {
    __builtin_amdgcn_global_load_lds(
        (const __attribute__((address_space(1))) void*)g,
        (__attribute__((address_space(3))) void*)l, 16, 0, 0);
}

static __device__ __forceinline__ unsigned int cvt_pk_bf16(float a, float b) {
    unsigned int d;
    asm("v_cvt_pk_bf16_f32 %0, %1, %2" : "=v"(d) : "v"(a), "v"(b));
    return d;  // lo half = bf16(a), hi half = bf16(b)
}

// XOR-swizzled LDS index (shorts) for [row][chunk-of-8-shorts] tiles with
// 64-short rows: slot = chunk ^ (row & 7). Breaks the 128B-row bank aliasing
// while staying global_load_lds-compatible (lane*16B contiguous).
#define SWZ(row, c) ((((row) * 8) + ((c) ^ ((row) & 7))) * 8)

// ---------------------------------------------------------------------------
// fp32 -> bf16 cast: y=0: x (4M elems), y=1..3: Wq/Wk/Wv (1M each)
// ---------------------------------------------------------------------------
__global__ __launch_bounds__(256) void cast_kernel(
    const float* __restrict__ X,  const float* __restrict__ Wq,
    const float* __restrict__ Wk, const float* __restrict__ Wv,
    unsigned short* __restrict__ xb,  unsigned short* __restrict__ wqb,
    unsigned short* __restrict__ wkb, unsigned short* __restrict__ wvb)
{
    const float* src; unsigned short* dst; int n;
    switch (blockIdx.y) {
        case 0:  src = X;  dst = xb;  n = B_ * S_ * E_; break;
        case 1:  src = Wq; dst = wqb; n = E_ * E_;      break;
        case 2:  src = Wk; dst = wkb; n = E_ * E_;      break;
        default: src = Wv; dst = wvb; n = E_ * E_;      break;
    }
    int i = (blockIdx.x * 256 + threadIdx.x) * 8;
    if (i >= n) return;
    float4 a = *(const float4*)(src + i);
    float4 b = *(const float4*)(src + i + 4);
    ushort4 lo, hi;
    lo.x = f2bf(a.x); lo.y = f2bf(a.y); lo.z = f2bf(a.z); lo.w = f2bf(a.w);
    hi.x = f2bf(b.x); hi.y = f2bf(b.y); hi.z = f2bf(b.z); hi.w = f2bf(b.w);
    *(ushort4*)(dst + i)     = lo;
    *(ushort4*)(dst + i + 4) = hi;
}

// ---------------------------------------------------------------------------
// bf16 MFMA projection GEMM (m97 structure + swizzled LDS):
// C[i,j] = sum_k A[i,k]*B[j,k]; 128x128 tile, BK=64, 4 waves, 4x4 frags.
// z=0: A=x, B=Wq -> q bf16 [B,H,S,D] scaled log2(e)/8 (exp2 softmax path)
// z=1: A=x, B=Wk -> k bf16 [B,H,S,D]
// z=2: A=Wv, B=x (swapped) -> v bf16 [B,H,D,S] with coalesced stores
//
// R14: bijective 8x12 XCD tiling. Grid (32,8,3) linearizes x-fastest, so
// hw XCD = l % 8. Assign each XCD an 8(m) x 12(n,z) work rectangle: both
// A-panels (8 x 256KB = 2MB) and B-panels (12 x 256KB = 3MB) stay
// L2-resident per XCD (before: every XCD fetched all 24 B panels).
// ---------------------------------------------------------------------------
__global__ __launch_bounds__(256, 4) void gemm_kernel(
    const unsigned short* __restrict__ xb,
    const unsigned short* __restrict__ wqb, const unsigned short* __restrict__ wkb,
    const unsigned short* __restrict__ wvb,
    const float* __restrict__ bq, const float* __restrict__ bk,
    const float* __restrict__ bv,
    unsigned short* __restrict__ qb, unsigned short* __restrict__ kb,
    unsigned short* __restrict__ vb)
{
    constexpr int BM = 128, BK = 64;
    __shared__ unsigned short As[BM * BK];
    __shared__ unsigned short Bs[BM * BK];

    const int t    = threadIdx.x;
    const int lane = t & 63;
    const int w    = t >> 6;
    const int l15  = lane & 15;
    const int quad = lane >> 4;
    const int wm   = w & 1;
    const int wn   = w >> 1;

    // --- XCD-tiled work assignment (bijective over 768 blocks) ---
    const int l   = blockIdx.x + (blockIdx.y << 5) + (blockIdx.z << 8);
    const int ix  = l & 7;          // XCD id (hw round-robin)
    const int p   = l >> 3;         // position within XCD's 96-block share
    const int x2  = (ix & 3) * 8 + (p & 7);         // m-block 0..31
    const int yz  = (ix >> 2) * 12 + (p >> 3);      // (n,z) 0..23
    const int m0  = x2 * BM;
    const int n0  = (yz & 7) * BM;
    const int z   = yz >> 3;

    const unsigned short *Ab, *Bb; const float* bias; unsigned short* outp;
    int i0, j0; float sc = 1.0f;
    if (z == 0)      { Ab = xb;  Bb = wqb; bias = bq; outp = qb; i0 = m0; j0 = n0;
                       sc = 0.125f * 1.44269504088896f; }
    else if (z == 1) { Ab = xb;  Bb = wkb; bias = bk; outp = kb; i0 = m0; j0 = n0; }
    else             { Ab = wvb; Bb = xb;  bias = bv; outp = vb; i0 = n0; j0 = m0; }

    const int lrow = lane >> 3;
    const int gch  = ((lane & 7) ^ (lrow & 7)) * 8;
    const int lsl  = (lane & 7) * 8;

    f32x4 acc[4][4];
    #pragma unroll
    for (int mt = 0; mt < 4; ++mt)
        #pragma unroll
        for (int nt = 0; nt < 4; ++nt)
            #pragma unroll
            for (int r = 0; r < 4; ++r) acc[mt][nt][r] = 0.f;

    for (int k0 = 0; k0 < E_; k0 += BK) {
        __syncthreads();
        #pragma unroll
        for (int is = 0; is < 4; ++is) {
            int r = (w * 4 + is) * 8 + lrow;
            gload16(Ab + (size_t)(i0 + r) * E_ + k0 + gch, &As[r * BK + lsl]);
            gload16(Bb + (size_t)(j0 + r) * E_ + k0 + gch, &Bs[r * BK + lsl]);
        }
        __syncthreads();

        #pragma unroll
        for (int ks = 0; ks < 2; ++ks) {
            bf16x8 af[4], bfr[4];
            #pragma unroll
            for (int mt = 0; mt < 4; ++mt)
                af[mt] = *(const bf16x8*)&As[SWZ(wm*64 + mt*16 + l15, ks*4 + quad)];
            #pragma unroll
            for (int nt = 0; nt < 4; ++nt)
                bfr[nt] = *(const bf16x8*)&Bs[SWZ(wn*64 + nt*16 + l15, ks*4 + quad)];
            #pragma unroll
            for (int mt = 0; mt < 4; ++mt)
                #pragma unroll
                for (int nt = 0; nt < 4; ++nt)
                    acc[mt][nt] = __builtin_amdgcn_mfma_f32_16x16x32_bf16(
                        af[mt], bfr[nt], acc[mt][nt], 0, 0, 0);
        }
    }

    if (z < 2) {
        float bj[4];
        #pragma unroll
        for (int nt = 0; nt < 4; ++nt) bj[nt] = bias[j0 + wn*64 + nt*16 + l15];
        #pragma unroll
        for (int mt = 0; mt < 4; ++mt) {
            #pragma unroll
            for (int r = 0; r < 4; ++r) {
                int i = i0 + wm*64 + mt*16 + quad*4 + r;
                int b = i >> 11, s = i & (S_ - 1);
                #pragma unroll
                for (int nt = 0; nt < 4; ++nt) {
                    int jj = j0 + wn*64 + nt*16 + l15;
                    int hh = jj >> 6, d = jj & 63;
                    outp[(((size_t)(b * H_ + hh) * S_) + s) * D_ + d] =
                        f2bf((acc[mt][nt][r] + bj[nt]) * sc);
                }
            }
        }
    } else {
        #pragma unroll
        for (int mt = 0; mt < 4; ++mt) {
            #pragma unroll
            for (int r = 0; r < 4; ++r) {
                int i = i0 + wm*64 + mt*16 + quad*4 + r;
                int hh = i >> 6, d = i & 63;
                float bi = bias[i];
                #pragma unroll
                for (int nt = 0; nt < 4; ++nt) {
                    int jj = j0 + wn*64 + nt*16 + l15;
                    int b = jj >> 11, s = jj & (S_ - 1);
                    outp[(((size_t)(b * H_ + hh) * D_) + d) * S_ + s] =
                        f2bf(acc[mt][nt][r] + bi);
                }
            }
        }
    }
}

// ---------------------------------------------------------------------------
// MFMA attention, R14: R9-exact skeleton (proven 48.2us) + T5 setprio.
//
// Ledger: R10 (L2-direct K/V frags) 74.6us -- fragment reads (lane stride
// S_*2B) are uncoalesced in global, must go through LDS. R11 (mt=4 @
// bounds(512,4)) 245us -- VGPR cap -> scratch spill. R12 (mt=4 @ 1 blk/CU)
// 68.7us -- LDS relief doesn't pay for halved occupancy. R13 (V-direct)
// 74.3us -- same uncoalesced-fragment mechanism as R10. Conclusion: the R9
// geometry (mt=2, wq=w&3/wk=w>>2, 2 blocks/CU, dbuf staging, in-register P)
// is the local optimum; pipes at MFMA 30 / VALU 43 / LDS ~50% -> stall-
// bound on the per-iter QK->exp->pack->PV dependency chain.
//
// R14 change: s_setprio(1) around the QK and PV MFMA clusters so the CU
// scheduler prefers MFMA-ready waves over waves in their VALU phase
// (T5; m191 attn +4-7%; mechanism needs wave role drift, present here
// between the per-iter barriers with 16 waves/CU).
// q pre-scaled by log2(e)/8 in gemm -> raw v_exp_f32 here.
// XCD swizzle: bh = (j&7)*4 + (j>>7) keeps each XCD on 4 bh (L2-resident).
// ---------------------------------------------------------------------------
__global__ __launch_bounds__(512, 4) void attn_kernel(
    const unsigned short* __restrict__ Q, const unsigned short* __restrict__ K,
    const unsigned short* __restrict__ V, float* __restrict__ out)
{
    constexpr int TQ = 128, TK = 128;
    // per buffer (16384 shorts = 32KB): Ks0 @0, Ks1 @4096, Vt0 @8192, Vt1 @12288
    __shared__ unsigned short KV[2][16384];
    __shared__ float          Dex[TQ];

    const int t    = threadIdx.x;
    const int lane = t & 63;
    const int w    = t >> 6;        // wave 0..7
    const int wq   = w & 3;         // q-group (32 rows)
    const int wk   = w >> 2;        // key half
    const int l15  = lane & 15;
    const int quad = lane >> 4;

    const int j    = blockIdx.x;
    const int bh   = (j & 7) * 4 + (j >> 7);
    const int q0   = ((j >> 3) & 15) * TQ;
    const int wq0  = q0 + wq * 32;  // this wave's query base (32 rows)

    const unsigned short* Qp = Q + (size_t)bh * S_ * D_;
    const unsigned short* Kp = K + (size_t)bh * S_ * D_;
    const unsigned short* Vp = V + (size_t)bh * D_ * S_;   // [d][s]

    // Q B-operand frags (n = q = l15), pre-scaled by log2(e)/8: [mt][ks]
    bf16x8 qf[2][2];
    #pragma unroll
    for (int mt = 0; mt < 2; ++mt)
        #pragma unroll
        for (int ks = 0; ks < 2; ++ks)
            qf[mt][ks] = *(const bf16x8*)(Qp + (size_t)(wq0 + mt*16 + l15) * D_
                                          + ks*32 + quad*8);

    bf16x8 ones;
    #pragma unroll
    for (int i = 0; i < 8; ++i) ones[i] = (short)0x3F80;   // bf16 1.0

    f32x4 Oacc[2][4];
    #pragma unroll
    for (int mt = 0; mt < 2; ++mt)
        #pragma unroll
        for (int nt = 0; nt < 4; ++nt)
            #pragma unroll
            for (int r = 0; r < 4; ++r) Oacc[mt][nt][r] = 0.f;
    f32x4 Dacc[2];
    #pragma unroll
    for (int mt = 0; mt < 2; ++mt)
        #pragma unroll
        for (int r = 0; r < 4; ++r) Dacc[mt][r] = 0.f;

    // staging: 512 threads, 1 gload16 per array each; rows 0..63
    const int srow = t >> 3;                          // 0..63
    const int gch  = ((t & 7) ^ (srow & 7)) * 8;      // swizzle-inverse (shorts)
    const unsigned short* kg0 = Kp + (size_t)srow * D_ + gch;          // keys 0..63
    const unsigned short* kg1 = Kp + (size_t)(srow + 64) * D_ + gch;   // keys 64..127
    const unsigned short* vg0 = Vp + (size_t)srow * S_ + gch;
    const unsigned short* vg1 = Vp + (size_t)srow * S_ + 64 + gch;

    // prologue: stage tile 0 into buffer 0
    {
        unsigned short* nb = KV[0];
        gload16(kg0, nb + t*8);
        gload16(kg1, nb + 4096 + t*8);
        gload16(vg0, nb + 8192 + t*8);
        gload16(vg1, nb + 12288 + t*8);
        kg0 += TK * D_; kg1 += TK * D_; vg0 += TK; vg1 += TK;
    }
    __syncthreads();                 // vmcnt drained -> buf0 ready

    int cur = 0;
    for (int k0 = 0; k0 < S_; k0 += TK) {
        // issue next-tile staging into the other buffer (overlaps compute)
        if (k0 + TK < S_) {
            unsigned short* nb = KV[cur ^ 1];
            gload16(kg0, nb + t*8);
            gload16(kg1, nb + 4096 + t*8);
            gload16(vg0, nb + 8192 + t*8);
            gload16(vg1, nb + 12288 + t*8);
            kg0 += TK * D_; kg1 += TK * D_; vg0 += TK; vg1 += TK;
        }
        const unsigned short* KsW = &KV[cur][wk * 4096];
        const unsigned short* VtW = &KV[cur][8192 + wk * 4096];

        // ---- S^T = K Q^T : 64 keys (4 kt of 16) x 32 q (2 mt) per wave ----
        f32x4 sacc[2][4];
        #pragma unroll
        for (int mt = 0; mt < 2; ++mt)
            #pragma unroll
            for (int kt = 0; kt < 4; ++kt)
                #pragma unroll
                for (int r = 0; r < 4; ++r) sacc[mt][kt][r] = 0.f;
        __builtin_amdgcn_s_setprio(1);
        #pragma unroll
        for (int kt = 0; kt < 4; ++kt) {
            bf16x8 kf0 = *(const bf16x8*)&KsW[SWZ(kt*16 + l15, quad)];
            bf16x8 kf1 = *(const bf16x8*)&KsW[SWZ(kt*16 + l15, 4 + quad)];
            #pragma unroll
            for (int mt = 0; mt < 2; ++mt) {
                sacc[mt][kt] = __builtin_amdgcn_mfma_f32_16x16x32_bf16(
                    kf0, qf[mt][0], sacc[mt][kt], 0, 0, 0);
                sacc[mt][kt] = __builtin_amdgcn_mfma_f32_16x16x32_bf16(
                    kf1, qf[mt][1], sacc[mt][kt], 0, 0, 0);
            }
        }
        __builtin_amdgcn_s_setprio(0);

        // ---- exp2 + (rare) inverted-window mask; pack to bf16 in-register --
        unsigned int dw[2][4][2];
        #pragma unroll
        for (int mt = 0; mt < 2; ++mt) {
            const int qt0 = wq0 + mt*16;
            #pragma unroll
            for (int kt = 0; kt < 4; ++kt) {
                const int kt0 = k0 + wk*64 + kt*16;
                const bool band = (unsigned)(qt0 - kt0 + 18) <= 36u;  // wave-uniform
                float p[4];
                if (band) {
                    #pragma unroll
                    for (int r = 0; r < 4; ++r) {
                        int dlt = (qt0 + l15) - (kt0 + quad*4 + r);
                        if (dlt < 0) dlt = -dlt;
                        p[r] = (dlt <= WIN_) ? 0.f
                             : __builtin_amdgcn_exp2f(sacc[mt][kt][r]);
                    }
                } else {
                    #pragma unroll
                    for (int r = 0; r < 4; ++r)
                        p[r] = __builtin_amdgcn_exp2f(sacc[mt][kt][r]);
                }
                dw[mt][kt][0] = cvt_pk_bf16(p[0], p[1]);   // keys quad*4+{0,1}
                dw[mt][kt][1] = cvt_pk_bf16(p[2], p[3]);   // keys quad*4+{2,3}
            }
        }

        // ---- lane-swap P into PV A-frags: lane needs keys ks*32+quad*8..+7 -
        bf16x8 pa[2][2];
        #pragma unroll
        for (int mt = 0; mt < 2; ++mt) {
            #pragma unroll
            for (int ks = 0; ks < 2; ++ks) {
                uintx2 s0 = __builtin_amdgcn_permlane32_swap(
                    dw[mt][2*ks][0], dw[mt][2*ks + 1][0], false, false);
                uintx2 a02 = __builtin_amdgcn_permlane16_swap(
                    s0.x, s0.y, false, false);
                uintx2 s1 = __builtin_amdgcn_permlane32_swap(
                    dw[mt][2*ks][1], dw[mt][2*ks + 1][1], false, false);
                uintx2 a13 = __builtin_amdgcn_permlane16_swap(
                    s1.x, s1.y, false, false);
                union { unsigned int d[4]; bf16x8 v; } u;
                u.d[0] = a02.x;   // keys quad*8+{0,1}
                u.d[1] = a13.x;   // keys quad*8+{2,3}
                u.d[2] = a02.y;   // keys quad*8+{4,5}
                u.d[3] = a13.y;   // keys quad*8+{6,7}
                pa[mt][ks] = u.v;
            }
        }

        // ---- O += P V ; D += P 1 over this wave's key half ----
        __builtin_amdgcn_s_setprio(1);
        #pragma unroll
        for (int ks = 0; ks < 2; ++ks) {
            #pragma unroll
            for (int mt = 0; mt < 2; ++mt)
                Dacc[mt] = __builtin_amdgcn_mfma_f32_16x16x32_bf16(
                    pa[mt][ks], ones, Dacc[mt], 0, 0, 0);
            #pragma unroll
            for (int nt = 0; nt < 4; ++nt) {
                bf16x8 vf = *(const bf16x8*)&VtW[SWZ(nt*16 + l15, ks*4 + quad)];
                #pragma unroll
                for (int mt = 0; mt < 2; ++mt)
                    Oacc[mt][nt] = __builtin_amdgcn_mfma_f32_16x16x32_bf16(
                        pa[mt][ks], vf, Oacc[mt][nt], 0, 0, 0);
            }
        }
        __builtin_amdgcn_s_setprio(0);

        __syncthreads();   // all waves done with KV[cur]; next buffer's loads
                           // drained by the barrier's vmcnt(0)
        cur ^= 1;
    }

    // ---- merge key halves through LDS (Oex aliases KV[0]; 32KB exact) ----
    float* Oex = (float*)KV[0];          // 8192 floats = 32 KB
    if (wk == 1) {
        #pragma unroll
        for (int mt = 0; mt < 2; ++mt) {
            #pragma unroll
            for (int r = 0; r < 4; ++r) {
                const int qrow = wq*32 + mt*16 + quad*4 + r;
                Dex[qrow] = Dacc[mt][r];             // 16 lanes same value: benign
                #pragma unroll
                for (int nt = 0; nt < 4; ++nt)
                    Oex[qrow * 64 + nt*16 + l15] = Oacc[mt][nt][r];
            }
        }
    }
    __syncthreads();                     // Oex/Dex visible
    if (wk == 0) {
        const int b  = bh >> 4;
        const int hh = bh & 15;
        #pragma unroll
        for (int mt = 0; mt < 2; ++mt) {
            #pragma unroll
            for (int r = 0; r < 4; ++r) {
                const int qrow = wq*32 + mt*16 + quad*4 + r;
                const float iv = 1.f / (Dacc[mt][r] + Dex[qrow]);
                const int qg = q0 + qrow;
                float* op = out + (((size_t)b * S_ + qg) * H_ + hh) * D_;
                #pragma unroll
                for (int nt = 0; nt < 4; ++nt)
                    op[nt*16 + l15] =
                        (Oacc[mt][nt][r] + Oex[qrow * 64 + nt*16 + l15]) * iv;
            }
        }
    }
}

extern "C" void kernel_launch(void* const* d_in, const int* in_sizes, int n_in,
                              void* d_out, int out_size, void* d_ws, size_t ws_size,
                              hipStream_t stream) {
    const float* x  = (const float*)d_in[0];
    const float* Wq = (const float*)d_in[1];
    const float* bq = (const float*)d_in[2];
    const float* Wk = (const float*)d_in[3];
    const float* bk = (const float*)d_in[4];
    const float* Wv = (const float*)d_in[5];
    const float* bv = (const float*)d_in[6];
    float* out = (float*)d_out;

    const size_t per = (size_t)B_ * H_ * S_ * D_;   // 4,194,304 elements
    const size_t wsz = (size_t)E_ * E_;             // 1,048,576
    unsigned short* qb  = (unsigned short*)d_ws;
    unsigned short* kb  = qb + per;
    unsigned short* vb  = kb + per;
    unsigned short* xbf = vb + per;
    unsigned short* wqb = xbf + per;
    unsigned short* wkb = wqb + wsz;
    unsigned short* wvb = wkb + wsz;

    dim3 cgrid((B_ * S_ * E_ + 2047) / 2048, 4);
    cast_kernel<<<cgrid, 256, 0, stream>>>(x, Wq, Wk, Wv, xbf, wqb, wkb, wvb);

    dim3 ggrid(B_ * S_ / 128, E_ / 128, 3);
    gemm_kernel<<<ggrid, 256, 0, stream>>>(xbf, wqb, wkb, wvb, bq, bk, bv, qb, kb, vb);

    attn_kernel<<<dim3(512), 512, 0, stream>>>(qb, kb, vb, out);
}